// Round 8
// baseline (581.268 us; speedup 1.0000x reference)
//
#include <hip/hip_runtime.h>

#define NN 8192
#define FIN 128
#define FOUT 64
#define NEGINF (-9e15f)
#define LALPHA 0.2f

typedef float f32x4 __attribute__((ext_vector_type(4)));
typedef float f32x2 __attribute__((ext_vector_type(2)));
typedef short short8 __attribute__((ext_vector_type(8)));
typedef unsigned long long ull;

__device__ __forceinline__ unsigned short f32_to_bf16(float x) {
  unsigned int u = __float_as_uint(x);
  u = (u + 0x7fffu + ((u >> 16) & 1u)) >> 16;
  return (unsigned short)u;
}
__device__ __forceinline__ float bf16_to_f32(unsigned short b) {
  return __uint_as_float(((unsigned int)b) << 16);
}

// Kernel 1 (unchanged, proven): Wh = h@W fp32, s1 = Wh@a1, s2 = Wh@a2, and Wh
// pre-swizzled into the MFMA B-fragment layout (bf16 hi) for coalesced loads.
__global__ __launch_bounds__(256) void gat_prep(
    const float* __restrict__ h, const float* __restrict__ W,
    const float* __restrict__ a,
    float* __restrict__ s1g, float* __restrict__ s2g,
    unsigned short* __restrict__ whfh)
{
  __shared__ __align__(16) float Wl[FIN * FOUT];
  __shared__ __align__(16) float hl[16 * FIN];
  const int tid = threadIdx.x;
  const int i0 = blockIdx.x * 16;
  #pragma unroll
  for (int it = 0; it < 8; ++it) {
    int idx = (it * 256 + tid) * 4;
    *(f32x4*)&Wl[idx] = *(const f32x4*)&W[idx];
  }
  #pragma unroll
  for (int it = 0; it < 2; ++it) {
    int idx = (it * 256 + tid) * 4;
    *(f32x4*)&hl[idx] = *(const f32x4*)&h[(size_t)i0 * FIN + idx];
  }
  __syncthreads();
  const int r = tid >> 4;
  const int f0 = (tid & 15) * 4;
  f32x4 acc = {0.f, 0.f, 0.f, 0.f};
  #pragma unroll 8
  for (int k = 0; k < FIN; ++k) {
    float hv = hl[r * FIN + k];
    f32x4 wv = *(const f32x4*)&Wl[k * FOUT + f0];
    acc += hv * wv;
  }
  f32x4 a1v = *(const f32x4*)&a[f0];
  f32x4 a2v = *(const f32x4*)&a[FOUT + f0];
  float p1 = acc.x * a1v.x + acc.y * a1v.y + acc.z * a1v.z + acc.w * a1v.w;
  float p2 = acc.x * a2v.x + acc.y * a2v.y + acc.z * a2v.z + acc.w * a2v.w;
  #pragma unroll
  for (int d = 1; d < 16; d <<= 1) {
    p1 += __shfl_xor(p1, d, 16);
    p2 += __shfl_xor(p2, d, 16);
  }
  const int j = i0 + r;  // row of Wh == K index of PV
  if ((tid & 15) == 0) { s1g[j] = p1; s2g[j] = p2; }
  // value Wh[k][n] -> frag[(kstep*4 + n/16)*512 + (((k%32)/8)*16 + n%16)*8 + k%8]
  const int kstep = j >> 5;
  const int lhi = (j >> 3) & 3;
  const int ein = j & 7;
  #pragma unroll
  for (int e = 0; e < 4; ++e) {
    int f = f0 + e;
    unsigned short hb = f32_to_bf16(acc[e]);
    int ln = lhi * 16 + (f & 15);
    whfh[(size_t)(kstep * 4 + (f >> 4)) * 512 + ln * 8 + ein] = hb;
  }
}

// Fused kernel, 256 blocks x 1024 threads (16 waves, 1 block/CU), 32 rows per
// block as 2 groups of 16, software-pipelined with wave specialization:
//   P1(g0) by all 16 waves
//   [ P2(g0) on waves 0-7  ||  P1(g1) on waves 8-15 ]   <- reads+writes MIXED
//   P2(g1) by waves 8-15
// launch_bounds(1024,4): VGPR cap 128 (r7's (1024,8) starved the kernel to 32
// VGPRs). maskl/rowp double-buffered; red separate (alive across phases).
__global__ __launch_bounds__(1024, 4) void gat_fused(
    const int* __restrict__ adj,
    const float* __restrict__ s1g, const float* __restrict__ s2g,
    const unsigned short* __restrict__ whfh,
    float* __restrict__ outh, float* __restrict__ outa)
{
  __shared__ __align__(16) float s2l[NN];                  // 32 KB
  __shared__ __align__(16) unsigned int maskl[2][16][258]; // 33 KB
  __shared__ __align__(16) float red[4][1024];             // 16 KB
  __shared__ float rowp[2][16][3];                         // s1, M, 1/l
  const int tid = threadIdx.x;
  const int lane = tid & 63;
  const int wv = tid >> 6;          // 0..15
  const int i0 = blockIdx.x * 32;   // 32 rows per block

  // ---- stage s2
  #pragma unroll
  for (int it = 0; it < 2; ++it) {
    int idx = (it * 1024 + tid) * 4;
    *(f32x4*)&s2l[idx] = *(const f32x4*)&s2g[idx];
  }
  __syncthreads();

  // ---- P1(g0): 16 waves, one row per wave; M = lrelu(s1) (row-consistent)
  {
    const float s1v = s1g[i0 + wv];
    const float M = fmaxf(s1v, LALPHA * s1v);
    const int* __restrict__ ar = adj + (size_t)(i0 + wv) * NN;
    float ls = 0.f;
    #pragma unroll 4
    for (int it = 0; it < 128; ++it) {
      int jj = it * 64 + lane;
      int a0 = __builtin_nontemporal_load(&ar[jj]);
      float sv = s2l[jj];
      ull b = __ballot(a0 > 0);
      float x = s1v + sv;
      x = fmaxf(x, LALPHA * x);
      float e = __expf(x - M);
      ls += (a0 > 0) ? e : 0.f;
      if (lane == 0) *(ull*)&maskl[0][wv][it * 2] = b;
    }
    #pragma unroll
    for (int d = 1; d < 64; d <<= 1) ls += __shfl_xor(ls, d);
    if (lane == 0) {
      rowp[0][wv][0] = s1v; rowp[0][wv][1] = M; rowp[0][wv][2] = 1.f / ls;
    }
  }
  __syncthreads();

  const int arow = lane & 15;   // A-row within the group's 16 rows
  const int kg = lane >> 4;     // k-block within fragment
  f32x4 acc0 = {0,0,0,0}, acc1 = {0,0,0,0}, acc2 = {0,0,0,0}, acc3 = {0,0,0,0};
  const short8* __restrict__ bfrag = (const short8*)whfh;

  // P2 for group g over K-range [kbase, kbase+1024): attention write + MFMA PV
  auto runP2 = [&](int g, int kbase) {
    const float s1r = rowp[g][arow][0];
    const float mr  = rowp[g][arow][1];
    const float rir = rowp[g][arow][2];
    float* __restrict__ orow = outa + (size_t)(i0 + g * 16 + arow) * NN;
    for (int step = 0; step < 16; ++step) {
      const int k0 = kbase + step * 64;
      #pragma unroll
      for (int half = 0; half < 2; ++half) {
        const int kh = k0 + half * 32;
        const int jb = kh + kg * 8;
        f32x4 sa = *(const f32x4*)&s2l[jb];
        f32x4 sb = *(const f32x4*)&s2l[jb + 4];
        unsigned int bits = maskl[g][arow][kh >> 5] >> (kg * 8);
        float s2v[8] = {sa.x, sa.y, sa.z, sa.w, sb.x, sb.y, sb.z, sb.w};
        float af[8];
        short8 AH, AL;
        #pragma unroll
        for (int e = 0; e < 8; ++e) {
          float x = s1r + s2v[e];
          x = fmaxf(x, LALPHA * x);
          x = ((bits >> e) & 1u) ? x : NEGINF;
          float p = __expf(x - mr) * rir;
          af[e] = p;
          unsigned short hb = f32_to_bf16(p);
          AH[e] = (short)hb;
          AL[e] = (short)f32_to_bf16(p - bf16_to_f32(hb));
        }
        f32x4 st0 = {af[0], af[1], af[2], af[3]};
        f32x4 st1 = {af[4], af[5], af[6], af[7]};
        *(f32x4*)&orow[jb] = st0;       // cached store: L2 merges lines
        *(f32x4*)&orow[jb + 4] = st1;
        size_t fb = (size_t)(kh >> 5) * 256 + lane;  // short8 units
        short8 B0 = bfrag[fb];
        short8 B1 = bfrag[fb + 64];
        short8 B2 = bfrag[fb + 128];
        short8 B3 = bfrag[fb + 192];
        acc0 = __builtin_amdgcn_mfma_f32_16x16x32_bf16(AH, B0, acc0, 0, 0, 0);
        acc1 = __builtin_amdgcn_mfma_f32_16x16x32_bf16(AH, B1, acc1, 0, 0, 0);
        acc2 = __builtin_amdgcn_mfma_f32_16x16x32_bf16(AH, B2, acc2, 0, 0, 0);
        acc3 = __builtin_amdgcn_mfma_f32_16x16x32_bf16(AH, B3, acc3, 0, 0, 0);
        acc0 = __builtin_amdgcn_mfma_f32_16x16x32_bf16(AL, B0, acc0, 0, 0, 0);
        acc1 = __builtin_amdgcn_mfma_f32_16x16x32_bf16(AL, B1, acc1, 0, 0, 0);
        acc2 = __builtin_amdgcn_mfma_f32_16x16x32_bf16(AL, B2, acc2, 0, 0, 0);
        acc3 = __builtin_amdgcn_mfma_f32_16x16x32_bf16(AL, B3, acc3, 0, 0, 0);
      }
    }
  };

  // ---- middle phase: waves 0-7 write g0 while waves 8-15 sweep adj for g1
  if (wv < 8) {
    runP2(0, wv * 1024);
  } else {
    const int rl0 = (wv - 8) * 2, rl1 = rl0 + 1;
    const float s1a = s1g[i0 + 16 + rl0];
    const float s1b = s1g[i0 + 16 + rl1];
    const float Ma = fmaxf(s1a, LALPHA * s1a);
    const float Mb = fmaxf(s1b, LALPHA * s1b);
    const int* __restrict__ ara = adj + (size_t)(i0 + 16 + rl0) * NN;
    const int* __restrict__ arb = adj + (size_t)(i0 + 16 + rl1) * NN;
    float la = 0.f, lb = 0.f;
    #pragma unroll 2
    for (int it = 0; it < 128; ++it) {
      int jj = it * 64 + lane;
      int a0 = __builtin_nontemporal_load(&ara[jj]);
      int a1 = __builtin_nontemporal_load(&arb[jj]);
      float sv = s2l[jj];
      ull b0 = __ballot(a0 > 0);
      ull b1 = __ballot(a1 > 0);
      float xa = s1a + sv; xa = fmaxf(xa, LALPHA * xa);
      float xb = s1b + sv; xb = fmaxf(xb, LALPHA * xb);
      la += (a0 > 0) ? __expf(xa - Ma) : 0.f;
      lb += (a1 > 0) ? __expf(xb - Mb) : 0.f;
      if (lane == 0) {
        *(ull*)&maskl[1][rl0][it * 2] = b0;
        *(ull*)&maskl[1][rl1][it * 2] = b1;
      }
    }
    #pragma unroll
    for (int d = 1; d < 64; d <<= 1) {
      la += __shfl_xor(la, d);
      lb += __shfl_xor(lb, d);
    }
    if (lane == 0) {
      rowp[1][rl0][0] = s1a; rowp[1][rl0][1] = Ma; rowp[1][rl0][2] = 1.f / la;
      rowp[1][rl1][0] = s1b; rowp[1][rl1][1] = Mb; rowp[1][rl1][2] = 1.f / lb;
    }
  }
  __syncthreads();

  // ---- reduce + outh for g0 (partials live in waves 0-7)
  {
    f32x4 av[4] = {acc0, acc1, acc2, acc3};
    float* slab = &red[wv & 3][0];
    if (wv < 4) {
      #pragma unroll
      for (int nt = 0; nt < 4; ++nt)
        #pragma unroll
        for (int rg = 0; rg < 4; ++rg)
          slab[(kg * 4 + rg) * 64 + nt * 16 + arow] = av[nt][rg];
    }
  }
  __syncthreads();
  {
    f32x4 av[4] = {acc0, acc1, acc2, acc3};
    float* slab = &red[wv & 3][0];
    if (wv >= 4 && wv < 8) {
      #pragma unroll
      for (int nt = 0; nt < 4; ++nt)
        #pragma unroll
        for (int rg = 0; rg < 4; ++rg)
          slab[(kg * 4 + rg) * 64 + nt * 16 + arow] += av[nt][rg];
    }
  }
  __syncthreads();
  if (tid < 512) {
    int base = tid * 2;
    f32x2 r0 = *(f32x2*)&red[0][base];
    f32x2 r1 = *(f32x2*)&red[1][base];
    f32x2 r2 = *(f32x2*)&red[2][base];
    f32x2 r3 = *(f32x2*)&red[3][base];
    f32x2 s = r0 + r1 + r2 + r3;
    *(f32x2*)&outh[(size_t)i0 * FOUT + base] = s;
  }

  // ---- final phase: waves 8-15 write g1 (waves 0-7 done; pass barriers)
  if (wv >= 8) runP2(1, (wv - 8) * 1024);
  __syncthreads();
  {
    f32x4 av[4] = {acc0, acc1, acc2, acc3};
    float* slab = &red[wv & 3][0];
    if (wv >= 8 && wv < 12) {
      #pragma unroll
      for (int nt = 0; nt < 4; ++nt)
        #pragma unroll
        for (int rg = 0; rg < 4; ++rg)
          slab[(kg * 4 + rg) * 64 + nt * 16 + arow] = av[nt][rg];
    }
  }
  __syncthreads();
  {
    f32x4 av[4] = {acc0, acc1, acc2, acc3};
    float* slab = &red[wv & 3][0];
    if (wv >= 12) {
      #pragma unroll
      for (int nt = 0; nt < 4; ++nt)
        #pragma unroll
        for (int rg = 0; rg < 4; ++rg)
          slab[(kg * 4 + rg) * 64 + nt * 16 + arow] += av[nt][rg];
    }
  }
  __syncthreads();
  if (tid >= 512) {
    int base = (tid - 512) * 2;
    f32x2 r0 = *(f32x2*)&red[0][base];
    f32x2 r1 = *(f32x2*)&red[1][base];
    f32x2 r2 = *(f32x2*)&red[2][base];
    f32x2 r3 = *(f32x2*)&red[3][base];
    f32x2 s = r0 + r1 + r2 + r3;
    *(f32x2*)&outh[(size_t)(i0 + 16) * FOUT + base] = s;
  }
}

extern "C" void kernel_launch(void* const* d_in, const int* in_sizes, int n_in,
                              void* d_out, int out_size, void* d_ws, size_t ws_size,
                              hipStream_t stream) {
  const float* h = (const float*)d_in[0];
  const int* adj = (const int*)d_in[1];
  const float* W = (const float*)d_in[2];
  const float* a = (const float*)d_in[3];
  float* outh = (float*)d_out;                    // h_prime [8192, 64]
  float* outa = outh + (size_t)NN * FOUT;         // attention [8192, 8192]
  char* ws = (char*)d_ws;                         // uses ~1.2 MB
  float* s1g = (float*)ws;
  float* s2g = s1g + NN;
  unsigned short* whfh = (unsigned short*)(ws + 128 * 1024);  // 1 MB B-fragments
  gat_prep<<<512, 256, 0, stream>>>(h, W, a, s1g, s2g, whfh);
  gat_fused<<<256, 1024, 0, stream>>>(adj, s1g, s2g, whfh, outh, outa);
}